// Round 6
// baseline (829.145 us; speedup 1.0000x reference)
//
#include <hip/hip_runtime.h>
#include <cstdint>
#include <cstddef>

// Problem constants (from reference): B=16, S=4096, C=512, A=0.5
#define PB 16
#define PS 4096
#define PC 512

// ---------------------------------------------------------------------------
// Single fused kernel. Grid = 4096 blocks x 256 threads; each block owns 16
// rows (4 per wave) of one batch (256 blocks per batch).
//
// Phase A (all blocks): register-direct row pass (argmax + lse + colsum),
//   identical structure to R5's k1 (measured <77 us, near the 19.5 us read
//   floor). lse/am published via atomicExch (device-scope visibility).
// Ticket: after a release fence, each block bumps bticket[b]; the block that
//   draws ticket 255 is the last of its batch -> runs the whole batch tail.
//   15 of 16 tails overlap with remaining phase-A blocks; only the last
//   batch's tail serializes (~5-8 us).
// Tail (one block per batch): LDS histogram -> shfl wave-scan (2 barriers,
//   was 18) -> LDS scatter -> per-class mode/eq/ne/val -> block reduce ->
//   acc atomics -> done-protocol; 16th tail writes out[0].
// ---------------------------------------------------------------------------
__global__ __launch_bounds__(256) void k_main(const float* __restrict__ pred,
                                              const int* __restrict__ target,
                                              int* __restrict__ am,
                                              float* __restrict__ lse,
                                              float* __restrict__ colsum,
                                              float* __restrict__ acc,
                                              int* __restrict__ done,
                                              int* __restrict__ bticket,
                                              float* __restrict__ out) {
    __shared__ float colred[4][PC];   // 8 KB  (phase A)
    __shared__ int   cnt[PC];         // 2 KB  (tail)
    __shared__ int   offsA[PC];       // 2 KB
    __shared__ int   cur[PC];         // 2 KB
    __shared__ int   sbucket[PS];     // 16 KB
    __shared__ float fred[4];
    __shared__ int   ired[4];
    __shared__ int   isLast;

    const int t = threadIdx.x, w = t >> 6, l = t & 63;
    const int rowBase = blockIdx.x * 16 + w * 4;   // 4 consecutive rows/wave
    const int b = blockIdx.x >> 8;                 // 256 blocks per batch
    const float* base = pred + (size_t)rowBase * PC + 4 * l;

    // ---- phase A ------------------------------------------------------
    // 8 independent coalesced float4 loads per thread (8 KB in flight/wave)
    float4 va[4], vb[4];
    #pragma unroll
    for (int r = 0; r < 4; ++r) {
        va[r] = *(const float4*)(base + r * PC);
        vb[r] = *(const float4*)(base + r * PC + 256);
    }

    // lane-local argmax (earliest index wins: strict >)
    float mv[4]; int mi[4];
    #pragma unroll
    for (int r = 0; r < 4; ++r) {
        float m = va[r].x; int i0 = 4 * l;
        if (va[r].y > m) { m = va[r].y; i0 = 4 * l + 1; }
        if (va[r].z > m) { m = va[r].z; i0 = 4 * l + 2; }
        if (va[r].w > m) { m = va[r].w; i0 = 4 * l + 3; }
        if (vb[r].x > m) { m = vb[r].x; i0 = 256 + 4 * l; }
        if (vb[r].y > m) { m = vb[r].y; i0 = 256 + 4 * l + 1; }
        if (vb[r].z > m) { m = vb[r].z; i0 = 256 + 4 * l + 2; }
        if (vb[r].w > m) { m = vb[r].w; i0 = 256 + 4 * l + 3; }
        mv[r] = m; mi[r] = i0;
    }

    // 4 interleaved butterflies (ILP=4 hides shuffle latency)
    #pragma unroll
    for (int off = 1; off < 64; off <<= 1) {
        #pragma unroll
        for (int r = 0; r < 4; ++r) {
            float ov = __shfl_xor(mv[r], off, 64);
            int   oi = __shfl_xor(mi[r], off, 64);
            if (ov > mv[r] || (ov == mv[r] && oi < mi[r])) { mv[r] = ov; mi[r] = oi; }
        }
    }

    float ss[4];
    #pragma unroll
    for (int r = 0; r < 4; ++r) {
        ss[r] = __expf(va[r].x - mv[r]) + __expf(va[r].y - mv[r])
              + __expf(va[r].z - mv[r]) + __expf(va[r].w - mv[r])
              + __expf(vb[r].x - mv[r]) + __expf(vb[r].y - mv[r])
              + __expf(vb[r].z - mv[r]) + __expf(vb[r].w - mv[r]);
    }
    #pragma unroll
    for (int off = 1; off < 64; off <<= 1) {
        #pragma unroll
        for (int r = 0; r < 4; ++r) ss[r] += __shfl_xor(ss[r], off, 64);
    }

    if (l == 0) {
        #pragma unroll
        for (int r = 0; r < 4; ++r) {
            atomicExch(&lse[rowBase + r], mv[r] + __logf(ss[r]));  // device-visible
            atomicExch(&am[rowBase + r], mi[r]);
        }
    }

    // column sums: lane l owns cols {4l..4l+3, 256+4l..4l+3} of its 4 rows
    colred[w][4 * l + 0] = va[0].x + va[1].x + va[2].x + va[3].x;
    colred[w][4 * l + 1] = va[0].y + va[1].y + va[2].y + va[3].y;
    colred[w][4 * l + 2] = va[0].z + va[1].z + va[2].z + va[3].z;
    colred[w][4 * l + 3] = va[0].w + va[1].w + va[2].w + va[3].w;
    colred[w][256 + 4 * l + 0] = vb[0].x + vb[1].x + vb[2].x + vb[3].x;
    colred[w][256 + 4 * l + 1] = vb[0].y + vb[1].y + vb[2].y + vb[3].y;
    colred[w][256 + 4 * l + 2] = vb[0].z + vb[1].z + vb[2].z + vb[3].z;
    colred[w][256 + 4 * l + 3] = vb[0].w + vb[1].w + vb[2].w + vb[3].w;
    __syncthreads();
    for (int c = t; c < PC; c += 256) {
        float s = colred[0][c] + colred[1][c] + colred[2][c] + colred[3][c];
        atomicAdd(&colsum[(b << 9) + c], s);
    }

    // ---- ticket: last block of batch b runs the tail -------------------
    __threadfence();      // release: publish lse/am/colsum before ticket
    __syncthreads();
    if (t == 0) isLast = (atomicAdd(&bticket[b], 1) == 255) ? 1 : 0;
    __syncthreads();
    if (!isLast) return;
    __threadfence();      // acquire: see all 256 blocks' writes

    // ---- tail for batch b ---------------------------------------------
    cnt[t] = 0; cnt[t + 256] = 0;
    __syncthreads();

    float lacc = 0.0f;
    for (int i = t; i < PS; i += 256) {
        int gi = (b << 12) + i;
        atomicAdd(&cnt[target[gi]], 1);   // LDS histogram
        lacc += lse[gi];
    }
    #pragma unroll
    for (int off = 1; off < 64; off <<= 1) lacc += __shfl_xor(lacc, off, 64);
    if (l == 0) fred[w] = lacc;
    __syncthreads();                      // cnt + fred ready
    float Ls = fred[0] + fred[1] + fred[2] + fred[3];

    // exclusive scan of cnt[512]: 2 classes/thread, shfl wave-scan
    int c0 = cnt[2 * t], c1 = cnt[2 * t + 1];
    int s2 = c0 + c1, incl = s2;
    #pragma unroll
    for (int off = 1; off < 64; off <<= 1) {
        int v = __shfl_up(incl, off, 64);
        if (l >= off) incl += v;
    }
    if (l == 63) ired[w] = incl;
    __syncthreads();
    int woff = 0;
    for (int j = 0; j < w; ++j) woff += ired[j];
    incl += woff;
    int e1 = incl - c1, e0 = e1 - c0;
    offsA[2 * t] = e0; offsA[2 * t + 1] = e1;
    cur[2 * t] = e0;   cur[2 * t + 1] = e1;
    __syncthreads();

    for (int i = t; i < PS; i += 256) {   // scatter (re-read target/am: L2-hot)
        int gi = (b << 12) + i;
        int tg = target[gi];
        int a  = am[gi];
        int pos = atomicAdd(&cur[tg], 1);
        sbucket[pos] = i | (a << 12);     // s:12 bits, am class above
    }
    __syncthreads();

    float vsA = 0.0f, ksA = 0.0f;
    for (int c = t; c < PC; c += 256) {   // 2 classes per thread
        int k = cnt[c];
        if (k > 0) {
            int start = offsA[c];
            int bc = 0, bvv = 0;          // mode, tie -> smallest class
            for (int i = 0; i < k; ++i) {
                int v = sbucket[start + i] >> 12;
                int cc = 0;
                for (int j = 0; j < k; ++j) cc += ((sbucket[start + j] >> 12) == v) ? 1 : 0;
                if (cc > bc || (cc == bc && v < bvv)) { bc = cc; bvv = v; }
            }
            int m = bvv;
            float lseSum = 0.0f, ep = 0.0f;
            for (int i = 0; i < k; ++i) {
                int s = sbucket[start + i] & (PS - 1);
                lseSum += lse[(b << 12) + s];
                ep += pred[(((size_t)(b << 12)) + s) * PC + m];
            }
            float eq_sum = lseSum - ep;
            float ne_sum = (Ls - colsum[(b << 9) + m]) - eq_sum;
            float nf = (float)k;
            float eq_loss = eq_sum / fmaxf(nf, 1.0f);
            float ne_mean = ne_sum / fmaxf((float)PS - nf, 1.0f);
            float ne_loss = 1.0f / ((ne_mean != 0.0f) ? ne_mean : 1.0f);
            float val = 0.5f * eq_loss + 0.5f * ne_loss;
            if (val != 0.0f) { vsA += val; ksA += 1.0f; }
        }
    }
    #pragma unroll
    for (int off = 1; off < 64; off <<= 1) {
        vsA += __shfl_xor(vsA, off, 64);
        ksA += __shfl_xor(ksA, off, 64);
    }
    if (l == 0) { fred[w] = vsA; ired[w] = __float_as_int(ksA); }
    __syncthreads();
    if (t == 0) {
        float sv = fred[0] + fred[1] + fred[2] + fred[3];
        float sk = __int_as_float(ired[0]) + __int_as_float(ired[1])
                 + __int_as_float(ired[2]) + __int_as_float(ired[3]);
        atomicAdd(&acc[0], sv);
        atomicAdd(&acc[1], sk);
        __threadfence();
        int d = atomicAdd(done, 1);
        if (d == PB - 1) {                // 16th (last) batch-tail finalizes
            __threadfence();
            float a0 = atomicAdd(&acc[0], 0.0f);
            float a1 = atomicAdd(&acc[1], 0.0f);
            out[0] = a0 / fmaxf(a1, 1.0f);
        }
    }
}

extern "C" void kernel_launch(void* const* d_in, const int* in_sizes, int n_in,
                              void* d_out, int out_size, void* d_ws, size_t ws_size,
                              hipStream_t stream) {
    const float* pred = (const float*)d_in[0];   // (B,S,C) f32
    const int* target = (const int*)d_in[1];     // (B,S) int
    float* out = (float*)d_out;

    char* w = (char*)d_ws;
    int*   am      = (int*)(w + 0);          // B*S ints   = 256 KiB
    float* lse     = (float*)(w + 262144);   // B*S floats = 256 KiB
    float* colsum  = (float*)(w + 524288);   // B*C floats =  32 KiB  <- memset 0
    float* acc     = (float*)(w + 557056);   // 2 floats             <- memset 0
    int*   done    = (int*)(w + 557064);     // 1 int                <- memset 0
    int*   bticket = (int*)(w + 557072);     // PB ints              <- memset 0

    // zero colsum + acc + done + bticket in one async memset (graph-capturable)
    hipMemsetAsync(w + 524288, 0, 557072 + PB * 4 - 524288, stream);
    k_main<<<(PB * PS) / 16, 256, 0, stream>>>(pred, target, am, lse, colsum,
                                               acc, done, bticket, out);
}

// Round 8
// 223.089 us; speedup vs baseline: 3.7167x; 3.7167x over previous
//
#include <hip/hip_runtime.h>
#include <cstdint>
#include <cstddef>

// Problem constants (from reference): B=16, S=4096, C=512, A=0.5
#define PB 16
#define PS 4096
#define PC 512

// native clang vector type: __builtin_nontemporal_load requires it
typedef float vf4 __attribute__((ext_vector_type(4)));

// ---------------------------------------------------------------------------
// K1: register-direct streaming pass (R5 structure — measured fastest).
// 4096 blocks x 256 thr; each wave owns 4 rows, issues all 8 float4 loads up
// front (8 KB in flight/wave). 4 interleaved butterfly chains (ILP=4).
// No barriers in hot path, 8 KB LDS only for the colsum reduce.
// NOTE (R6 lesson): NO __threadfence / device-scope publication here — the
// per-XCD L2 writeback serialized 4096 blocks (709 us). Kernel-boundary
// ordering makes plain stores visible to the tail kernel.
// NOTE (R4 lesson): no min-waves launch bound — VGPR squeeze serializes loads.
// ---------------------------------------------------------------------------
__global__ __launch_bounds__(256) void k1_rows(const float* __restrict__ pred,
                                               int* __restrict__ am,
                                               float* __restrict__ lse,
                                               float* __restrict__ colsum) {
    const int t = threadIdx.x, w = t >> 6, l = t & 63;
    const int rowBase = blockIdx.x * 16 + w * 4;   // 4 consecutive rows per wave
    const int b = rowBase >> 12;                   // PS = 4096
    const float* base = pred + (size_t)rowBase * PC + 4 * l;

    // 8 independent coalesced nontemporal loads (stream-once data)
    vf4 va[4], vb[4];
    #pragma unroll
    for (int r = 0; r < 4; ++r) {
        va[r] = __builtin_nontemporal_load((const vf4*)(base + r * PC));
        vb[r] = __builtin_nontemporal_load((const vf4*)(base + r * PC + 256));
    }

    // lane-local argmax over 8 elements per row (earliest index wins: strict >)
    float mv[4]; int mi[4];
    #pragma unroll
    for (int r = 0; r < 4; ++r) {
        float m = va[r].x; int i0 = 4 * l;
        if (va[r].y > m) { m = va[r].y; i0 = 4 * l + 1; }
        if (va[r].z > m) { m = va[r].z; i0 = 4 * l + 2; }
        if (va[r].w > m) { m = va[r].w; i0 = 4 * l + 3; }
        if (vb[r].x > m) { m = vb[r].x; i0 = 256 + 4 * l; }
        if (vb[r].y > m) { m = vb[r].y; i0 = 256 + 4 * l + 1; }
        if (vb[r].z > m) { m = vb[r].z; i0 = 256 + 4 * l + 2; }
        if (vb[r].w > m) { m = vb[r].w; i0 = 256 + 4 * l + 3; }
        mv[r] = m; mi[r] = i0;
    }

    // 4 interleaved butterflies: (max, min-index-on-tie) is assoc+comm
    #pragma unroll
    for (int off = 1; off < 64; off <<= 1) {
        #pragma unroll
        for (int r = 0; r < 4; ++r) {
            float ov = __shfl_xor(mv[r], off, 64);
            int   oi = __shfl_xor(mi[r], off, 64);
            if (ov > mv[r] || (ov == mv[r] && oi < mi[r])) { mv[r] = ov; mi[r] = oi; }
        }
    }

    // exp sums (mv[r] is now the true row max)
    float ss[4];
    #pragma unroll
    for (int r = 0; r < 4; ++r) {
        ss[r] = __expf(va[r].x - mv[r]) + __expf(va[r].y - mv[r])
              + __expf(va[r].z - mv[r]) + __expf(va[r].w - mv[r])
              + __expf(vb[r].x - mv[r]) + __expf(vb[r].y - mv[r])
              + __expf(vb[r].z - mv[r]) + __expf(vb[r].w - mv[r]);
    }
    #pragma unroll
    for (int off = 1; off < 64; off <<= 1) {
        #pragma unroll
        for (int r = 0; r < 4; ++r) ss[r] += __shfl_xor(ss[r], off, 64);
    }

    float l0 = mv[0] + __logf(ss[0]);
    float l1 = mv[1] + __logf(ss[1]);
    float l2 = mv[2] + __logf(ss[2]);
    float l3 = mv[3] + __logf(ss[3]);

    if (l == 0) {
        *(float4*)(lse + rowBase) = make_float4(l0, l1, l2, l3);   // 16B aligned
        *(int4*)(am + rowBase) = make_int4(mi[0], mi[1], mi[2], mi[3]);
    }

    // column sums: lane l owns cols {4l..4l+3, 256+4l..256+4l+3} of its 4 rows
    float cs0 = va[0].x + va[1].x + va[2].x + va[3].x;
    float cs1 = va[0].y + va[1].y + va[2].y + va[3].y;
    float cs2 = va[0].z + va[1].z + va[2].z + va[3].z;
    float cs3 = va[0].w + va[1].w + va[2].w + va[3].w;
    float cs4 = vb[0].x + vb[1].x + vb[2].x + vb[3].x;
    float cs5 = vb[0].y + vb[1].y + vb[2].y + vb[3].y;
    float cs6 = vb[0].z + vb[1].z + vb[2].z + vb[3].z;
    float cs7 = vb[0].w + vb[1].w + vb[2].w + vb[3].w;

    __shared__ float lds[4][PC];   // 8 KB
    lds[w][4 * l + 0] = cs0; lds[w][4 * l + 1] = cs1;
    lds[w][4 * l + 2] = cs2; lds[w][4 * l + 3] = cs3;
    lds[w][256 + 4 * l + 0] = cs4; lds[w][256 + 4 * l + 1] = cs5;
    lds[w][256 + 4 * l + 2] = cs6; lds[w][256 + 4 * l + 3] = cs7;
    __syncthreads();
    for (int c = t; c < PC; c += 256) {
        float s = lds[0][c] + lds[1][c] + lds[2][c] + lds[3][c];
        atomicAdd(&colsum[(b << 9) + c], s);   // all 4 waves share b
    }
}

// ---------------------------------------------------------------------------
// K_TAIL: one block (512 threads) per batch; batch-local in LDS (R5-proven).
// pass1: target/am/lse -> LDS + histogram + Lsum; Hillis-Steele scan;
// LDS-cursor scatter; per-class mode/eq/ne/val; block reduce -> acc atomics;
// done-protocol finalize.
// ---------------------------------------------------------------------------
__global__ __launch_bounds__(512) void k_tail(const float* __restrict__ pred,
                                              const int* __restrict__ target,
                                              const int* __restrict__ am,
                                              const float* __restrict__ lse,
                                              const float* __restrict__ colsum,
                                              float* __restrict__ acc,
                                              int* __restrict__ done,
                                              float* __restrict__ out) {
    __shared__ int   tgam[PS];     // 16 KB: target | am<<16
    __shared__ float ldsLse[PS];   // 16 KB
    __shared__ int   sbucket[PS];  // 16 KB: s | am<<12
    __shared__ int   sc[PC];       // 2 KB
    __shared__ int   cur[PC];      // 2 KB
    __shared__ float red[8], redv[8], redk[8];

    const int b = blockIdx.x, t = threadIdx.x;
    cur[t] = 0;
    __syncthreads();

    float lacc = 0.0f;
    for (int i = t; i < PS; i += 512) {
        int gi = (b << 12) + i;
        int tg = target[gi];
        int a  = am[gi];
        float lv = lse[gi];
        tgam[i] = tg | (a << 16);
        ldsLse[i] = lv;
        lacc += lv;
        atomicAdd(&cur[tg], 1);    // LDS histogram
    }
    #pragma unroll
    for (int off = 1; off < 64; off <<= 1) lacc += __shfl_xor(lacc, off, 64);
    if ((t & 63) == 0) red[t >> 6] = lacc;
    __syncthreads();
    float Ls = red[0] + red[1] + red[2] + red[3] + red[4] + red[5] + red[6] + red[7];

    int x = cur[t];                // count for class t
    sc[t] = x;
    __syncthreads();
    for (int off = 1; off < PC; off <<= 1) {   // Hillis-Steele inclusive scan
        int v = (t >= off) ? sc[t - off] : 0;
        __syncthreads();
        sc[t] += v;
        __syncthreads();
    }
    int start = sc[t] - x;         // exclusive offset within batch
    cur[t] = start;
    __syncthreads();
    for (int i = t; i < PS; i += 512) {        // scatter from LDS only
        int e = tgam[i];
        int tg = e & 0xFFFF, a = e >> 16;
        int pos = atomicAdd(&cur[tg], 1);
        sbucket[pos] = i | (a << 12);
    }
    __syncthreads();

    int k = x;
    float val = 0.0f; int keep = 0;
    if (k > 0) {
        // mode of am over the bucket; tie -> smallest class (order-independent)
        int bc = 0, bvv = 0;
        for (int i = 0; i < k; ++i) {
            int v = sbucket[start + i] >> 12;
            int c = 0;
            for (int j = 0; j < k; ++j) c += ((sbucket[start + j] >> 12) == v) ? 1 : 0;
            if (c > bc || (c == bc && v < bvv)) { bc = c; bvv = v; }
        }
        int m = bvv;
        float lseSum = 0.0f;
        float ep0 = 0.0f, ep1 = 0.0f;
        const float* pb = pred + (size_t)(b << 12) * PC + m;
        int i = 0;
        for (; i + 1 < k; i += 2) {            // 2-way unroll: 2 loads in flight
            int s0 = sbucket[start + i] & (PS - 1);
            int s1 = sbucket[start + i + 1] & (PS - 1);
            lseSum += ldsLse[s0] + ldsLse[s1];
            ep0 += pb[(size_t)s0 * PC];
            ep1 += pb[(size_t)s1 * PC];
        }
        if (i < k) {
            int s0 = sbucket[start + i] & (PS - 1);
            lseSum += ldsLse[s0];
            ep0 += pb[(size_t)s0 * PC];
        }
        float eq_sum = lseSum - (ep0 + ep1);
        float ne_sum = (Ls - colsum[(b << 9) + m]) - eq_sum;
        float nf = (float)k;
        float eq_loss = eq_sum / fmaxf(nf, 1.0f);
        float ne_mean = ne_sum / fmaxf((float)PS - nf, 1.0f);
        float ne_loss = 1.0f / ((ne_mean != 0.0f) ? ne_mean : 1.0f);
        val = 0.5f * eq_loss + 0.5f * ne_loss;
        keep = (val != 0.0f) ? 1 : 0;
    }

    float vs = keep ? val : 0.0f;
    float ks = (float)keep;
    #pragma unroll
    for (int off = 1; off < 64; off <<= 1) {
        vs += __shfl_xor(vs, off, 64);
        ks += __shfl_xor(ks, off, 64);
    }
    if ((t & 63) == 0) { redv[t >> 6] = vs; redk[t >> 6] = ks; }
    __syncthreads();
    if (t == 0) {
        float sv = 0.0f, sk = 0.0f;
        #pragma unroll
        for (int i2 = 0; i2 < 8; ++i2) { sv += redv[i2]; sk += redk[i2]; }
        atomicAdd(&acc[0], sv);
        atomicAdd(&acc[1], sk);
        __threadfence();
        int d = atomicAdd(done, 1);
        if (d == PB - 1) {                      // last batch-block finalizes
            __threadfence();
            float a0 = atomicAdd(&acc[0], 0.0f);
            float a1 = atomicAdd(&acc[1], 0.0f);
            out[0] = a0 / fmaxf(a1, 1.0f);
        }
    }
}

extern "C" void kernel_launch(void* const* d_in, const int* in_sizes, int n_in,
                              void* d_out, int out_size, void* d_ws, size_t ws_size,
                              hipStream_t stream) {
    const float* pred = (const float*)d_in[0];   // (B,S,C) f32
    const int* target = (const int*)d_in[1];     // (B,S) int
    float* out = (float*)d_out;

    char* w = (char*)d_ws;
    int*   am     = (int*)(w + 0);          // B*S ints   = 256 KiB
    float* lse    = (float*)(w + 262144);   // B*S floats = 256 KiB
    float* colsum = (float*)(w + 524288);   // B*C floats =  32 KiB  <- memset 0
    float* acc    = (float*)(w + 557056);   // 2 floats             <- memset 0
    int*   done   = (int*)(w + 557064);     // 1 int                <- memset 0

    // zero colsum + acc + done in one async memset (graph-capturable)
    (void)hipMemsetAsync(w + 524288, 0, 32768 + 12, stream);
    k1_rows<<<(PB * PS) / 16, 256, 0, stream>>>(pred, am, lse, colsum);
    k_tail<<<PB, 512, 0, stream>>>(pred, target, am, lse, colsum, acc, done, out);
}

// Round 9
// 218.721 us; speedup vs baseline: 3.7909x; 1.0200x over previous
//
#include <hip/hip_runtime.h>
#include <cstdint>
#include <cstddef>

// Problem constants (from reference): B=16, S=4096, C=512, A=0.5
#define PB 16
#define PS 4096
#define PC 512

// ---------------------------------------------------------------------------
// K1: register-direct streaming pass (R5 structure — measured fastest).
// 4096 blocks x 256 thr; each wave owns 4 rows, issues all 8 float4 loads up
// front (8 KB in flight/wave; 16 waves/CU -> ~128 KB/CU in flight).
// 4 interleaved butterfly chains (ILP=4). Plain loads (NOT nontemporal: the
// harness's d_in restore re-writes pred through L3 every iteration, so ~half
// the reads are L3 hits — nt loads forfeited that, R8 = +2.5 us).
// NOTE (R6): no __threadfence / device-scope publication — per-XCD L2
// writeback serialized 4096 blocks (709 us). Kernel boundary orders stores.
// NOTE (R4): no min-waves launch bound — VGPR squeeze serializes loads.
// ---------------------------------------------------------------------------
__global__ __launch_bounds__(256) void k1_rows(const float* __restrict__ pred,
                                               int* __restrict__ am,
                                               float* __restrict__ lse,
                                               float* __restrict__ colsum) {
    const int t = threadIdx.x, w = t >> 6, l = t & 63;
    const int rowBase = blockIdx.x * 16 + w * 4;   // 4 consecutive rows per wave
    const int b = rowBase >> 12;                   // PS = 4096
    const float* base = pred + (size_t)rowBase * PC + 4 * l;

    float4 va[4], vb[4];
    #pragma unroll
    for (int r = 0; r < 4; ++r) {
        va[r] = *(const float4*)(base + r * PC);
        vb[r] = *(const float4*)(base + r * PC + 256);
    }

    // lane-local argmax over 8 elements per row (earliest index wins: strict >)
    float mv[4]; int mi[4];
    #pragma unroll
    for (int r = 0; r < 4; ++r) {
        float m = va[r].x; int i0 = 4 * l;
        if (va[r].y > m) { m = va[r].y; i0 = 4 * l + 1; }
        if (va[r].z > m) { m = va[r].z; i0 = 4 * l + 2; }
        if (va[r].w > m) { m = va[r].w; i0 = 4 * l + 3; }
        if (vb[r].x > m) { m = vb[r].x; i0 = 256 + 4 * l; }
        if (vb[r].y > m) { m = vb[r].y; i0 = 256 + 4 * l + 1; }
        if (vb[r].z > m) { m = vb[r].z; i0 = 256 + 4 * l + 2; }
        if (vb[r].w > m) { m = vb[r].w; i0 = 256 + 4 * l + 3; }
        mv[r] = m; mi[r] = i0;
    }

    // 4 interleaved butterflies: (max, min-index-on-tie) is assoc+comm
    #pragma unroll
    for (int off = 1; off < 64; off <<= 1) {
        #pragma unroll
        for (int r = 0; r < 4; ++r) {
            float ov = __shfl_xor(mv[r], off, 64);
            int   oi = __shfl_xor(mi[r], off, 64);
            if (ov > mv[r] || (ov == mv[r] && oi < mi[r])) { mv[r] = ov; mi[r] = oi; }
        }
    }

    // exp sums (mv[r] is now the true row max)
    float ss[4];
    #pragma unroll
    for (int r = 0; r < 4; ++r) {
        ss[r] = __expf(va[r].x - mv[r]) + __expf(va[r].y - mv[r])
              + __expf(va[r].z - mv[r]) + __expf(va[r].w - mv[r])
              + __expf(vb[r].x - mv[r]) + __expf(vb[r].y - mv[r])
              + __expf(vb[r].z - mv[r]) + __expf(vb[r].w - mv[r]);
    }
    #pragma unroll
    for (int off = 1; off < 64; off <<= 1) {
        #pragma unroll
        for (int r = 0; r < 4; ++r) ss[r] += __shfl_xor(ss[r], off, 64);
    }

    float l0 = mv[0] + __logf(ss[0]);
    float l1 = mv[1] + __logf(ss[1]);
    float l2 = mv[2] + __logf(ss[2]);
    float l3 = mv[3] + __logf(ss[3]);

    if (l == 0) {
        *(float4*)(lse + rowBase) = make_float4(l0, l1, l2, l3);   // 16B aligned
        *(int4*)(am + rowBase) = make_int4(mi[0], mi[1], mi[2], mi[3]);
    }

    // column sums: lane l owns cols {4l..4l+3, 256+4l..256+4l+3} of its 4 rows
    float cs0 = va[0].x + va[1].x + va[2].x + va[3].x;
    float cs1 = va[0].y + va[1].y + va[2].y + va[3].y;
    float cs2 = va[0].z + va[1].z + va[2].z + va[3].z;
    float cs3 = va[0].w + va[1].w + va[2].w + va[3].w;
    float cs4 = vb[0].x + vb[1].x + vb[2].x + vb[3].x;
    float cs5 = vb[0].y + vb[1].y + vb[2].y + vb[3].y;
    float cs6 = vb[0].z + vb[1].z + vb[2].z + vb[3].z;
    float cs7 = vb[0].w + vb[1].w + vb[2].w + vb[3].w;

    __shared__ float lds[4][PC];   // 8 KB
    lds[w][4 * l + 0] = cs0; lds[w][4 * l + 1] = cs1;
    lds[w][4 * l + 2] = cs2; lds[w][4 * l + 3] = cs3;
    lds[w][256 + 4 * l + 0] = cs4; lds[w][256 + 4 * l + 1] = cs5;
    lds[w][256 + 4 * l + 2] = cs6; lds[w][256 + 4 * l + 3] = cs7;
    __syncthreads();
    for (int c = t; c < PC; c += 256) {
        float s = lds[0][c] + lds[1][c] + lds[2][c] + lds[3][c];
        atomicAdd(&colsum[(b << 9) + c], s);   // all 4 waves share b
    }
}

// ---------------------------------------------------------------------------
// K_TAIL: one block (1024 threads) per batch. Vectorized pass-1 into
// registers (4 elems/thread via int4/float4 — no tgam LDS pass), LDS
// histogram, shfl wave-scan (2 barriers, was 18 Hillis-Steele rounds),
// register scatter, per-class mode/eq/ne/val, block reduce -> acc atomics,
// done-protocol finalize.
// ---------------------------------------------------------------------------
__global__ __launch_bounds__(1024) void k_tail(const float* __restrict__ pred,
                                               const int* __restrict__ target,
                                               const int* __restrict__ am,
                                               const float* __restrict__ lse,
                                               const float* __restrict__ colsum,
                                               float* __restrict__ acc,
                                               int* __restrict__ done,
                                               float* __restrict__ out) {
    __shared__ float ldsLse[PS];   // 16 KB
    __shared__ int   sbucket[PS];  // 16 KB: s | am<<12
    __shared__ int   cnt[PC];      // 2 KB
    __shared__ int   offsA[PC];    // 2 KB
    __shared__ int   cur[PC];      // 2 KB
    __shared__ float redL[16];
    __shared__ int   redS[8];
    __shared__ float redv[16], redk[16];

    const int b = blockIdx.x, t = threadIdx.x, w = t >> 6, l = t & 63;
    if (t < PC) cnt[t] = 0;
    __syncthreads();

    // pass 1: 4 consecutive elements per thread, fully vectorized
    const int4*   tg4p = (const int4*)(target + (b << 12));
    const int4*   am4p = (const int4*)(am + (b << 12));
    const float4* ls4p = (const float4*)(lse + (b << 12));
    int4 tg4 = tg4p[t];
    int4 am4 = am4p[t];
    float4 ls4 = ls4p[t];
    ((float4*)ldsLse)[t] = ls4;
    atomicAdd(&cnt[tg4.x], 1);
    atomicAdd(&cnt[tg4.y], 1);
    atomicAdd(&cnt[tg4.z], 1);
    atomicAdd(&cnt[tg4.w], 1);
    float lacc = ls4.x + ls4.y + ls4.z + ls4.w;
    #pragma unroll
    for (int off = 1; off < 64; off <<= 1) lacc += __shfl_xor(lacc, off, 64);
    if (l == 0) redL[w] = lacc;
    __syncthreads();                       // cnt, ldsLse, redL ready
    float Ls = 0.0f;
    #pragma unroll
    for (int j = 0; j < 16; ++j) Ls += redL[j];

    // exclusive scan over 512 classes: threads 0..511 (waves 0..7), shfl scan
    int x = 0, incl = 0;
    if (t < PC) {
        x = cnt[t];
        incl = x;
        #pragma unroll
        for (int off = 1; off < 64; off <<= 1) {
            int v = __shfl_up(incl, off, 64);
            if (l >= off) incl += v;
        }
        if (l == 63) redS[w] = incl;
    }
    __syncthreads();
    if (t < PC) {
        int woff = 0;
        #pragma unroll
        for (int j = 0; j < 8; ++j) woff += (j < w) ? redS[j] : 0;
        int excl = incl + woff - x;
        offsA[t] = excl;
        cur[t] = excl;
    }
    __syncthreads();

    // scatter from registers (elements 4t..4t+3)
    {
        int pos;
        pos = atomicAdd(&cur[tg4.x], 1); sbucket[pos] = (4 * t + 0) | (am4.x << 12);
        pos = atomicAdd(&cur[tg4.y], 1); sbucket[pos] = (4 * t + 1) | (am4.y << 12);
        pos = atomicAdd(&cur[tg4.z], 1); sbucket[pos] = (4 * t + 2) | (am4.z << 12);
        pos = atomicAdd(&cur[tg4.w], 1); sbucket[pos] = (4 * t + 3) | (am4.w << 12);
    }
    __syncthreads();

    // per-class eval: thread t < 512 owns class t
    float val = 0.0f; int keep = 0;
    if (t < PC && x > 0) {
        int k = x, start = offsA[t];
        int bc = 0, bvv = 0;               // mode; tie -> smallest class
        for (int i = 0; i < k; ++i) {
            int v = sbucket[start + i] >> 12;
            int c = 0;
            for (int j = 0; j < k; ++j) c += ((sbucket[start + j] >> 12) == v) ? 1 : 0;
            if (c > bc || (c == bc && v < bvv)) { bc = c; bvv = v; }
        }
        int m = bvv;
        float lseSum = 0.0f, ep0 = 0.0f, ep1 = 0.0f;
        const float* pb = pred + (size_t)(b << 12) * PC + m;
        int i = 0;
        for (; i + 1 < k; i += 2) {        // 2-way unroll: 2 loads in flight
            int s0 = sbucket[start + i] & (PS - 1);
            int s1 = sbucket[start + i + 1] & (PS - 1);
            lseSum += ldsLse[s0] + ldsLse[s1];
            ep0 += pb[(size_t)s0 * PC];
            ep1 += pb[(size_t)s1 * PC];
        }
        if (i < k) {
            int s0 = sbucket[start + i] & (PS - 1);
            lseSum += ldsLse[s0];
            ep0 += pb[(size_t)s0 * PC];
        }
        float eq_sum = lseSum - (ep0 + ep1);
        float ne_sum = (Ls - colsum[(b << 9) + m]) - eq_sum;
        float nf = (float)k;
        float eq_loss = eq_sum / fmaxf(nf, 1.0f);
        float ne_mean = ne_sum / fmaxf((float)PS - nf, 1.0f);
        float ne_loss = 1.0f / ((ne_mean != 0.0f) ? ne_mean : 1.0f);
        val = 0.5f * eq_loss + 0.5f * ne_loss;
        keep = (val != 0.0f) ? 1 : 0;
    }

    float vs = keep ? val : 0.0f;
    float ks = (float)keep;
    #pragma unroll
    for (int off = 1; off < 64; off <<= 1) {
        vs += __shfl_xor(vs, off, 64);
        ks += __shfl_xor(ks, off, 64);
    }
    if (l == 0) { redv[w] = vs; redk[w] = ks; }
    __syncthreads();
    if (t == 0) {
        float sv = 0.0f, sk = 0.0f;
        #pragma unroll
        for (int j = 0; j < 16; ++j) { sv += redv[j]; sk += redk[j]; }
        atomicAdd(&acc[0], sv);
        atomicAdd(&acc[1], sk);
        __threadfence();
        int d = atomicAdd(done, 1);
        if (d == PB - 1) {                 // last batch-block finalizes
            __threadfence();
            float a0 = atomicAdd(&acc[0], 0.0f);
            float a1 = atomicAdd(&acc[1], 0.0f);
            out[0] = a0 / fmaxf(a1, 1.0f);
        }
    }
}

extern "C" void kernel_launch(void* const* d_in, const int* in_sizes, int n_in,
                              void* d_out, int out_size, void* d_ws, size_t ws_size,
                              hipStream_t stream) {
    const float* pred = (const float*)d_in[0];   // (B,S,C) f32
    const int* target = (const int*)d_in[1];     // (B,S) int
    float* out = (float*)d_out;

    char* w = (char*)d_ws;
    int*   am     = (int*)(w + 0);          // B*S ints   = 256 KiB
    float* lse    = (float*)(w + 262144);   // B*S floats = 256 KiB
    float* colsum = (float*)(w + 524288);   // B*C floats =  32 KiB  <- memset 0
    float* acc    = (float*)(w + 557056);   // 2 floats             <- memset 0
    int*   done   = (int*)(w + 557064);     // 1 int                <- memset 0

    (void)hipMemsetAsync(w + 524288, 0, 32768 + 12, stream);
    k1_rows<<<(PB * PS) / 16, 256, 0, stream>>>(pred, am, lse, colsum);
    k_tail<<<PB, 1024, 0, stream>>>(pred, target, am, lse, colsum, acc, done, out);
}